// Round 10
// baseline (231.233 us; speedup 1.0000x reference)
//
#include <hip/hip_runtime.h>
#include <cstddef>

#define N_ENT   2000
#define GAT_EMB 64
#define HIDDEN  256
#define BATCH   8
#define ALPHA   0.2f
#define NROWS   (BATCH * N_ENT)   // 16000

typedef _Float16 half4 __attribute__((ext_vector_type(4)));
typedef unsigned long long u64;

// ws byte layout:
//   [0,      8192)    s2f  float[2048]      (pad zeroed by k_prep)
//   [8192,  12288)    hx   _Float16[2048]   (pad zeroed)
//   [12288, 16384)    hy   _Float16[2048]
//   [16384, 20480)    hz   _Float16[2048]
//   [20480, 28672)    s1f  float[2048]
//   [28672, 124672)   x16  _Float16[6000][8]
//   [124672, 4220672) masks u64[16000][32]  (bit l of masks[row][4c+q] = adj[row][256c+4l+q])
#define WS_HX_OFF      8192
#define WS_HY_OFF      12288
#define WS_HZ_OFF      16384
#define WS_S1_OFF      20480
#define WS_X_OFF       28672
#define WS_MASK_OFF    124672
#define WS_TIER2_BYTES 4220672

__global__ __launch_bounds__(256) void k_init(const float* __restrict__ fc1_b,
                                              float* __restrict__ out) {
    int idx = blockIdx.x * 256 + threadIdx.x;
    out[idx] = fc1_b[idx & (HIDDEN - 1)];
}

// Table build; 2048 threads cover the pad (zeroed).
__global__ __launch_bounds__(256) void k_prep(const float* __restrict__ emb,
                                              const float* __restrict__ W,
                                              const float* __restrict__ a,
                                              float* __restrict__ ws) {
    __shared__ float sW[GAT_EMB * 3];
    __shared__ float sa[6];
    int t = threadIdx.x;
    if (t < GAT_EMB * 3) sW[t] = W[t];
    if (t < 6)           sa[t] = a[t];
    __syncthreads();
    int i = blockIdx.x * 256 + t;
    if (i >= 2048) return;
    if (i >= N_ENT) {
        ws[i] = 0.f;
        ((_Float16*)((char*)ws + WS_HX_OFF))[i] = (_Float16)0;
        ((_Float16*)((char*)ws + WS_HY_OFF))[i] = (_Float16)0;
        ((_Float16*)((char*)ws + WS_HZ_OFF))[i] = (_Float16)0;
        ws[WS_S1_OFF / 4 + i] = 0.f;
        return;
    }
    const float4* er = (const float4*)(emb + (size_t)i * GAT_EMB);
    float h0 = 0.f, h1 = 0.f, h2 = 0.f;
#pragma unroll
    for (int k4 = 0; k4 < GAT_EMB / 4; ++k4) {
        float4 e4 = er[k4];
        int k = 4 * k4;
        h0 += e4.x * sW[(k + 0) * 3 + 0]; h1 += e4.x * sW[(k + 0) * 3 + 1]; h2 += e4.x * sW[(k + 0) * 3 + 2];
        h0 += e4.y * sW[(k + 1) * 3 + 0]; h1 += e4.y * sW[(k + 1) * 3 + 1]; h2 += e4.y * sW[(k + 1) * 3 + 2];
        h0 += e4.z * sW[(k + 2) * 3 + 0]; h1 += e4.z * sW[(k + 2) * 3 + 1]; h2 += e4.z * sW[(k + 2) * 3 + 2];
        h0 += e4.w * sW[(k + 3) * 3 + 0]; h1 += e4.w * sW[(k + 3) * 3 + 1]; h2 += e4.w * sW[(k + 3) * 3 + 2];
    }
    ws[i] = h0 * sa[3] + h1 * sa[4] + h2 * sa[5];                       // s2
    ((_Float16*)((char*)ws + WS_HX_OFF))[i] = (_Float16)h0;
    ((_Float16*)((char*)ws + WS_HY_OFF))[i] = (_Float16)h1;
    ((_Float16*)((char*)ws + WS_HZ_OFF))[i] = (_Float16)h2;
    ws[WS_S1_OFF / 4 + i] = h0 * sa[0] + h1 * sa[1] + h2 * sa[2];       // s1
}

// Pure streamer: adj (128 MB) -> bitmasks (4 MB). One wave per row; 8 unrolled
// dwordx4 loads (no LDS, no carried deps, minimal consume) -> deep VMEM pipeline.
__global__ __launch_bounds__(256) void k_pack(const int* __restrict__ adj,
                                              u64* __restrict__ masks) {
    int t = threadIdx.x, lane = t & 63, w = t >> 6;
    int row = blockIdx.x * 4 + w;                 // [0, 16000)
    const int* __restrict__ rp = adj + (size_t)row * N_ENT;
    u64* __restrict__ mp = masks + (size_t)row * 32;
#pragma unroll
    for (int c = 0; c < 8; ++c) {
        int j0 = c * 256 + lane * 4;
        int jc = (j0 < N_ENT) ? j0 : 0;           // tail lanes: garbage bits, consumer ignores
        int4 m = *(const int4*)(rp + jc);
        u64 b0 = __ballot(m.x > 0);
        u64 b1 = __ballot(m.y > 0);
        u64 b2 = __ballot(m.z > 0);
        u64 b3 = __ballot(m.w > 0);
        if (lane < 4) {
            u64 v = (lane == 0) ? b0 : (lane == 1) ? b1 : (lane == 2) ? b2 : b3;
            mp[c * 4 + lane] = v;
        }
    }
}

// GAT on bitmasks: 1000 blocks x 16 rows (one batch b each). Wave w: rows +4w..+3.
// Per chunk per row: one 16B + one 16B broadcast mask load (L2-hot), bit-test
// replaces the 1 KB adj read. Table in LDS (20.5 KB), numerics identical.
__global__ __launch_bounds__(256, 4) void k_gat(const u64* __restrict__ masks,
                                                const float* __restrict__ wsf,
                                                float* __restrict__ wsx) {
    __shared__ __align__(16) unsigned char smem[20480];
    float*    s2s = (float*)smem;
    _Float16* hxs = (_Float16*)(smem + 8192);
    _Float16* hys = (_Float16*)(smem + 12288);
    _Float16* hzs = (_Float16*)(smem + 16384);
    __shared__ float s1sh[16];

    int t = threadIdx.x;
    int R0 = blockIdx.x * 16;
    int b  = R0 / N_ENT;
    int i_base = R0 - b * N_ENT;

    {
        const uint4* src = (const uint4*)wsf;
        uint4* dst = (uint4*)smem;
#pragma unroll
        for (int rep = 0; rep < 5; ++rep) dst[rep * 256 + t] = src[rep * 256 + t];  // 20480 B (pad pre-zeroed)
        if (t < 16) s1sh[t] = wsf[WS_S1_OFF / 4 + i_base + t];
    }
    __syncthreads();

    int lane = t & 63;
    int w    = t >> 6;
    float s1r[4];
    const u64* __restrict__ mrow[4];
#pragma unroll
    for (int r = 0; r < 4; ++r) {
        s1r[r] = s1sh[4 * w + r];
        mrow[r] = masks + (size_t)(R0 + 4 * w + r) * 32;
    }

    float acc[4][4];
#pragma unroll
    for (int r = 0; r < 4; ++r) { acc[r][0] = 0.f; acc[r][1] = 0.f; acc[r][2] = 0.f; acc[r][3] = 0.f; }

    int l4 = lane << 2;
#pragma unroll
    for (int c = 0; c < 8; ++c) {
        int j0 = c * 256 + l4;                  // <= 2044; LDS pad zeroed
        bool valid = (j0 < N_ENT);
        float vw = valid ? 1.0f : 0.0f;
        // masks for this chunk: 4 rows x 4 u64 (broadcast loads, L2-hot)
        u64 mq[4][4];
#pragma unroll
        for (int r = 0; r < 4; ++r) {
            ulonglong2 ma = *(const ulonglong2*)(mrow[r] + c * 4);
            ulonglong2 mb = *(const ulonglong2*)(mrow[r] + c * 4 + 2);
            mq[r][0] = ma.x; mq[r][1] = ma.y; mq[r][2] = mb.x; mq[r][3] = mb.y;
        }
        float4 s2v = *(const float4*)&s2s[j0];
        half4  hxv = *(const half4*)&hxs[j0];
        half4  hyv = *(const half4*)&hys[j0];
        half4  hzv = *(const half4*)&hzs[j0];
        float hx[4], hy[4], hz[4];
#pragma unroll
        for (int q = 0; q < 4; ++q) { hx[q] = (float)hxv[q]; hy[q] = (float)hyv[q]; hz[q] = (float)hzv[q]; }
#pragma unroll
        for (int r = 0; r < 4; ++r) {
#pragma unroll
            for (int q = 0; q < 4; ++q) {
                float e  = s1r[r] + ((const float*)&s2v)[q];
                float ev = __expf(fmaxf(e, 0.f) + ALPHA * fminf(e, 0.f));
                bool on = (mq[r][q] >> lane) & 1ull;
                float contrib = (on ? ev : 1.0f) * vw;   // expf(9e-15)==1.0f exactly
                acc[r][0] += contrib;
                acc[r][1] += contrib * hx[q];
                acc[r][2] += contrib * hy[q];
                acc[r][3] += contrib * hz[q];
            }
        }
    }

#pragma unroll
    for (int off = 32; off > 0; off >>= 1)
#pragma unroll
        for (int r = 0; r < 4; ++r) {
            acc[r][0] += __shfl_xor(acc[r][0], off, 64);
            acc[r][1] += __shfl_xor(acc[r][1], off, 64);
            acc[r][2] += __shfl_xor(acc[r][2], off, 64);
            acc[r][3] += __shfl_xor(acc[r][3], off, 64);
        }

    if (lane == 0) {
        _Float16* x16 = (_Float16*)((char*)wsx + WS_X_OFF);
#pragma unroll
        for (int r = 0; r < 4; ++r) {
            float inv = 1.f / acc[r][0];
            float p0 = acc[r][1] * inv, p1 = acc[r][2] * inv, p2 = acc[r][3] * inv;
            p0 = (p0 > 0.f) ? p0 : expm1f(p0);   // ELU
            p1 = (p1 > 0.f) ? p1 : expm1f(p1);
            p2 = (p2 > 0.f) ? p2 : expm1f(p2);
            int i = i_base + 4 * w + r;
            x16[(size_t)(3 * i + 0) * 8 + b] = (_Float16)p0;
            x16[(size_t)(3 * i + 1) * 8 + b] = (_Float16)p1;
            x16[(size_t)(3 * i + 2) * 8 + b] = (_Float16)p2;
        }
    }
}

// out[b,k] = fc1_b[k] + sum_m x16[m][b] * fc1_w[k][m]; 256 blocks (one per k).
__global__ __launch_bounds__(256) void k_fc(const _Float16* __restrict__ x16,
                                            const float* __restrict__ fc1_w,
                                            const float* __restrict__ fc1_b,
                                            float* __restrict__ out) {
    __shared__ float red[4][8];
    int t = threadIdx.x, lane = t & 63, w = t >> 6;
    int k = blockIdx.x;
    const float* __restrict__ wr = fc1_w + (size_t)k * (N_ENT * 3);
    float acc[BATCH];
#pragma unroll
    for (int b = 0; b < BATCH; ++b) acc[b] = 0.f;
#pragma unroll
    for (int it = 0; it < 6; ++it) {
        int m0 = 4 * t + 1024 * it;
        if (m0 + 3 < N_ENT * 3) {
            float4 wv4 = *(const float4*)(wr + m0);
#pragma unroll
            for (int q = 0; q < 4; ++q) {
                half4 xa = *(const half4*)(x16 + (size_t)(m0 + q) * 8);
                half4 xb = *(const half4*)(x16 + (size_t)(m0 + q) * 8 + 4);
                float wv = ((const float*)&wv4)[q];
                acc[0] += wv * (float)xa[0]; acc[1] += wv * (float)xa[1];
                acc[2] += wv * (float)xa[2]; acc[3] += wv * (float)xa[3];
                acc[4] += wv * (float)xb[0]; acc[5] += wv * (float)xb[1];
                acc[6] += wv * (float)xb[2]; acc[7] += wv * (float)xb[3];
            }
        }
    }
#pragma unroll
    for (int off = 32; off > 0; off >>= 1)
#pragma unroll
        for (int b = 0; b < BATCH; ++b) acc[b] += __shfl_xor(acc[b], off, 64);
    if (lane == 0)
#pragma unroll
        for (int b = 0; b < BATCH; ++b) red[w][b] = acc[b];
    __syncthreads();
    if (t < 8)
        out[t * HIDDEN + k] = red[0][t] + red[1][t] + red[2][t] + red[3][t] + fc1_b[k];
}

// ---- Fallback (small/no workspace): self-contained, atomic FC ----
__global__ __launch_bounds__(256, 5) void k_main_fb(const float* __restrict__ emb,
                                                    const float* __restrict__ W,
                                                    const float* __restrict__ a,
                                                    const float* __restrict__ fc1_w,
                                                    const int*   __restrict__ adj,
                                                    float* __restrict__ out) {
    __shared__ __align__(16) unsigned char smem[20480];
    float*    s2s = (float*)smem;
    _Float16* hxs = (_Float16*)(smem + 8192);
    _Float16* hys = (_Float16*)(smem + 12288);
    _Float16* hzs = (_Float16*)(smem + 16384);
    __shared__ float sW[GAT_EMB * 3];
    __shared__ float sa[6];
    __shared__ float s1sh[16];
    __shared__ float xblk[48];

    int t = threadIdx.x;
    int R0 = blockIdx.x * 16;
    int b  = R0 / N_ENT;
    int i_base = R0 - b * N_ENT;

    if (t < GAT_EMB * 3) sW[t] = W[t];
    if (t < 6)           sa[t] = a[t];
    __syncthreads();
    for (int j = t; j < N_ENT; j += 256) {
        const float4* er = (const float4*)(emb + (size_t)j * GAT_EMB);
        float h0 = 0.f, h1 = 0.f, h2 = 0.f;
#pragma unroll
        for (int k4 = 0; k4 < GAT_EMB / 4; ++k4) {
            float4 e4 = er[k4];
            int k = 4 * k4;
            h0 += e4.x * sW[(k + 0) * 3 + 0]; h1 += e4.x * sW[(k + 0) * 3 + 1]; h2 += e4.x * sW[(k + 0) * 3 + 2];
            h0 += e4.y * sW[(k + 1) * 3 + 0]; h1 += e4.y * sW[(k + 1) * 3 + 1]; h2 += e4.y * sW[(k + 1) * 3 + 2];
            h0 += e4.z * sW[(k + 2) * 3 + 0]; h1 += e4.z * sW[(k + 2) * 3 + 1]; h2 += e4.z * sW[(k + 2) * 3 + 2];
            h0 += e4.w * sW[(k + 3) * 3 + 0]; h1 += e4.w * sW[(k + 3) * 3 + 1]; h2 += e4.w * sW[(k + 3) * 3 + 2];
        }
        s2s[j] = h0 * sa[3] + h1 * sa[4] + h2 * sa[5];
        hxs[j] = (_Float16)h0; hys[j] = (_Float16)h1; hzs[j] = (_Float16)h2;
        if (j >= i_base && j < i_base + 16)
            s1sh[j - i_base] = h0 * sa[0] + h1 * sa[1] + h2 * sa[2];
    }
    if (t < 2048 - N_ENT) {
        int j = N_ENT + t;
        s2s[j] = 0.f; hxs[j] = (_Float16)0; hys[j] = (_Float16)0; hzs[j] = (_Float16)0;
    }
    __syncthreads();

    int lane = t & 63;
    int w    = t >> 6;
    float s1r[4];
    const int* __restrict__ rowp[4];
#pragma unroll
    for (int r = 0; r < 4; ++r) {
        s1r[r] = s1sh[4 * w + r];
        rowp[r] = adj + ((size_t)b * N_ENT + (i_base + 4 * w + r)) * N_ENT;
    }
    float acc[4][4];
#pragma unroll
    for (int r = 0; r < 4; ++r) { acc[r][0] = 0.f; acc[r][1] = 0.f; acc[r][2] = 0.f; acc[r][3] = 0.f; }
    int l4 = lane << 2;
#pragma unroll
    for (int c = 0; c < 8; ++c) {
        int j0 = c * 256 + l4;
        bool valid = (j0 < N_ENT);
        int jc = valid ? j0 : 0;
        int4 m0 = *(const int4*)(rowp[0] + jc);
        int4 m1 = *(const int4*)(rowp[1] + jc);
        int4 m2 = *(const int4*)(rowp[2] + jc);
        int4 m3 = *(const int4*)(rowp[3] + jc);
        float4 s2v = *(const float4*)&s2s[j0];
        half4  hxv = *(const half4*)&hxs[j0];
        half4  hyv = *(const half4*)&hys[j0];
        half4  hzv = *(const half4*)&hzs[j0];
        float hx[4], hy[4], hz[4];
#pragma unroll
        for (int q = 0; q < 4; ++q) { hx[q] = (float)hxv[q]; hy[q] = (float)hyv[q]; hz[q] = (float)hzv[q]; }
        const int* mm[4] = { (const int*)&m0, (const int*)&m1, (const int*)&m2, (const int*)&m3 };
        float vw = valid ? 1.0f : 0.0f;
#pragma unroll
        for (int r = 0; r < 4; ++r)
#pragma unroll
            for (int q = 0; q < 4; ++q) {
                float e  = s1r[r] + ((const float*)&s2v)[q];
                float ev = __expf(fmaxf(e, 0.f) + ALPHA * fminf(e, 0.f));
                float contrib = ((mm[r][q] > 0) ? ev : 1.0f) * vw;
                acc[r][0] += contrib; acc[r][1] += contrib * hx[q];
                acc[r][2] += contrib * hy[q]; acc[r][3] += contrib * hz[q];
            }
    }
#pragma unroll
    for (int off = 32; off > 0; off >>= 1)
#pragma unroll
        for (int r = 0; r < 4; ++r) {
            acc[r][0] += __shfl_xor(acc[r][0], off, 64);
            acc[r][1] += __shfl_xor(acc[r][1], off, 64);
            acc[r][2] += __shfl_xor(acc[r][2], off, 64);
            acc[r][3] += __shfl_xor(acc[r][3], off, 64);
        }
    if (lane == 0)
#pragma unroll
        for (int r = 0; r < 4; ++r) {
            float inv = 1.f / acc[r][0];
            float p0 = acc[r][1] * inv, p1 = acc[r][2] * inv, p2 = acc[r][3] * inv;
            int cc = 3 * (4 * w + r);
            xblk[cc + 0] = (p0 > 0.f) ? p0 : expm1f(p0);
            xblk[cc + 1] = (p1 > 0.f) ? p1 : expm1f(p1);
            xblk[cc + 2] = (p2 > 0.f) ? p2 : expm1f(p2);
        }
    __syncthreads();
    int k = (t + R0) & 255;
    const float* wr = fc1_w + (size_t)k * (N_ENT * 3) + 3 * i_base;
    float d = 0.f;
#pragma unroll
    for (int c4 = 0; c4 < 12; ++c4) {
        float4 wv = *(const float4*)(wr + 4 * c4);
        d += xblk[4 * c4 + 0] * wv.x + xblk[4 * c4 + 1] * wv.y
           + xblk[4 * c4 + 2] * wv.z + xblk[4 * c4 + 3] * wv.w;
    }
    atomicAdd(&out[b * HIDDEN + k], d);
}

extern "C" void kernel_launch(void* const* d_in, const int* in_sizes, int n_in,
                              void* d_out, int out_size, void* d_ws, size_t ws_size,
                              hipStream_t stream) {
    const float* emb   = (const float*)d_in[0];
    const float* W     = (const float*)d_in[1];
    const float* a     = (const float*)d_in[2];
    const float* fc1_w = (const float*)d_in[3];
    const float* fc1_b = (const float*)d_in[4];
    const int*   adj   = (const int*)d_in[5];
    float* out = (float*)d_out;
    float* ws  = (float*)d_ws;
    (void)in_sizes; (void)n_in; (void)out_size;

    if (ws_size >= (size_t)WS_TIER2_BYTES) {
        k_prep<<<8, 256, 0, stream>>>(emb, W, a, ws);
        k_pack<<<NROWS / 4, 256, 0, stream>>>(adj, (u64*)((char*)d_ws + WS_MASK_OFF));
        k_gat<<<1000, 256, 0, stream>>>((const u64*)((char*)d_ws + WS_MASK_OFF), ws, ws);
        k_fc<<<HIDDEN, 256, 0, stream>>>((const _Float16*)((char*)d_ws + WS_X_OFF),
                                         fc1_w, fc1_b, out);
    } else {
        k_init<<<8, 256, 0, stream>>>(fc1_b, out);
        k_main_fb<<<1000, 256, 0, stream>>>(emb, W, a, fc1_w, adj, out);
    }
}